// Round 7
// baseline (57.982 us; speedup 1.0000x reference)
//
#include <hip/hip_runtime.h>

#define BATCH  8
#define NPTS   16384
#define LVOX   605     // 11*11*5 = 121 xy-columns * 5 z
#define ABINS  8
#define CH     23
#define NCOL   121
#define SPTS   64      // points per 128-lane group
#define GRPS   2       // groups per block (256 threads)
#define BPTS   (SPTS * GRPS)          // 128 points per feature block
#define FEAT_BLOCKS (BATCH * (NPTS / BPTS))   // 8*128 = 1024
#define ROT_CH    4
#define ROT_CHPTS (NPTS / ROT_CH)             // 4096
#define ROT_BLOCKS (ABINS * BATCH * ROT_CH)   // 256

#define ROT_WS_INTS (ABINS * BATCH * LVOX)    // 38720 ints  = 154880 B
#define FEAT_WS_ULL (BATCH * LVOX * 4)        // 19360 ull   = 154880 B
#define WS_ULL_TOTAL (ROT_WS_INTS / 2 + FEAT_WS_ULL)   // 38720 ull

#define MASK8  0x0F0F0F0F0F0F0F0Full
#define MASK16 0x00FF00FF00FF00FFull

// ---------------------------------------------------------------------------
// Workspace zeroing (310 KB) — own kernel, no hipMemsetAsync.
// ---------------------------------------------------------------------------
__global__ __launch_bounds__(256) void zero_kernel(unsigned long long* __restrict__ ws) {
    const int i = blockIdx.x * 256 + threadIdx.x;
    if (i < WS_ULL_TOTAL) ws[i] = 0ull;
}

// ---------------------------------------------------------------------------
// Fused kernel, 256 threads (2 x 128-lane groups -> 20.6 KB LDS, high
// occupancy + scheduling slack).  Blocks [0,1024): distance features.
// Lane = xy-column, 5 z-locs per lane share rxy2; 64 points per group via
// wave-uniform scalar loads.  Nibble-packed bins -> byte counters -> LDS
// combine -> packed-16-bit global atomics.
// Blocks [1024,1280): rotation-voxel histogram (a,b) x 4 point chunks.
// ---------------------------------------------------------------------------
__global__ __launch_bounds__(256) void main_kernel(const float* __restrict__ pcd,
                                                   int* __restrict__ rot_hist,
                                                   unsigned long long* __restrict__ feat_hist) {
    __shared__ unsigned long long lds[5][2][GRPS][129];   // 20.6 KB
    const int bid = blockIdx.x;
    const int tid = threadIdx.x;

    if (bid < FEAT_BLOCKS) {
        const int b     = bid >> 7;       // /128
        const int outer = bid & 127;
        // group id is wave-uniform (128 = 2 waves); prove it for s_load.
        const int g4 = __builtin_amdgcn_readfirstlane(tid >> 7);
        const int li = tid & 127;
        const int cc = (li < NCOL) ? li : (NCOL - 1);
        const float lx = -5.0f + (float)(cc / 11);
        const float ly = -5.0f + (float)(cc % 11);

        const float* __restrict__ pp =
            pcd + ((size_t)b * NPTS + outer * BPTS + g4 * SPTS) * 3;

        unsigned long long be0 = 0, bo0 = 0, be1 = 0, bo1 = 0, be2 = 0, bo2 = 0,
                           be3 = 0, bo3 = 0, be4 = 0, bo4 = 0;

        // bin = floor(d) (== ceil(d)-1 a.e.); geometry => bin <= 13, no clamp.
#define PT(J)                                                                   \
        {                                                                       \
            const float x  = pp[(J) * 3 + 0];                                   \
            const float y  = pp[(J) * 3 + 1];                                   \
            const float zp = pp[(J) * 3 + 2];                                   \
            const float dx = x - lx, dy = y - ly;                               \
            const float rxy2 = fmaf(dy, dy, dx * dx);                           \
            const float dz0 = zp + 2.0f;                                        \
            { const float dz = dz0;        const float d = __builtin_amdgcn_sqrtf(fmaf(dz, dz, rxy2)); n0 += 1ull << (((int)d) << 2); } \
            { const float dz = dz0 - 1.0f; const float d = __builtin_amdgcn_sqrtf(fmaf(dz, dz, rxy2)); n1 += 1ull << (((int)d) << 2); } \
            { const float dz = dz0 - 2.0f; const float d = __builtin_amdgcn_sqrtf(fmaf(dz, dz, rxy2)); n2 += 1ull << (((int)d) << 2); } \
            { const float dz = dz0 - 3.0f; const float d = __builtin_amdgcn_sqrtf(fmaf(dz, dz, rxy2)); n3 += 1ull << (((int)d) << 2); } \
            { const float dz = dz0 - 4.0f; const float d = __builtin_amdgcn_sqrtf(fmaf(dz, dz, rxy2)); n4 += 1ull << (((int)d) << 2); } \
        }

#define MERGE()                                                                 \
        be0 += n0 & MASK8; bo0 += (n0 >> 4) & MASK8;                            \
        be1 += n1 & MASK8; bo1 += (n1 >> 4) & MASK8;                            \
        be2 += n2 & MASK8; bo2 += (n2 >> 4) & MASK8;                            \
        be3 += n3 & MASK8; bo3 += (n3 >> 4) & MASK8;                            \
        be4 += n4 & MASK8; bo4 += (n4 >> 4) & MASK8;

#pragma unroll 1
        for (int grp = 0; grp < 4; ++grp) {       // 4 groups of 15 points
            const int base = grp * 15;
            unsigned long long n0 = 0, n1 = 0, n2 = 0, n3 = 0, n4 = 0;
#pragma unroll
            for (int j = 0; j < 15; ++j) PT(base + j)
            MERGE()
        }
        {                                          // tail: points 60..63
            unsigned long long n0 = 0, n1 = 0, n2 = 0, n3 = 0, n4 = 0;
#pragma unroll
            for (int j = 60; j < 64; ++j) PT(j)
            MERGE()
        }
#undef PT
#undef MERGE

        lds[0][0][g4][li] = be0;  lds[0][1][g4][li] = bo0;
        lds[1][0][g4][li] = be1;  lds[1][1][g4][li] = bo1;
        lds[2][0][g4][li] = be2;  lds[2][1][g4][li] = bo2;
        lds[3][0][g4][li] = be3;  lds[3][1][g4][li] = bo3;
        lds[4][0][g4][li] = be4;  lds[4][1][g4][li] = bo4;
        __syncthreads();

        // combine groups (byte domain -> 16-bit domain), 2 atomics per item
        for (int item = tid; item < LVOX * 2; item += 256) {
            const int loc = item >> 1;
            const int eo  = item & 1;
            const int col = loc / 5;
            const int z   = loc % 5;
            unsigned long long slo = 0, shi = 0;
#pragma unroll
            for (int g = 0; g < GRPS; ++g) {
                const unsigned long long v = lds[z][eo][g][col];
                slo += v & MASK16;
                shi += (v >> 8) & MASK16;
            }
            unsigned long long* __restrict__ dst =
                feat_hist + ((size_t)b * LVOX + loc) * 4 + eo * 2;
            atomicAdd(&dst[0], slo);
            atomicAdd(&dst[1], shi);
        }
    } else {
        // ------------------ rotation-voxel histogram ------------------
        const int rb    = bid - FEAT_BLOCKS;
        const int ab    = rb & 63;        // a*8 + b
        const int chunk = rb >> 6;        // 0..3
        const int a     = ab >> 3;
        const int b     = ab & 7;

        int* h = (int*)lds;
        for (int i = tid; i < LVOX; i += 256) h[i] = 0;
        __syncthreads();

        const float C[8] = { -4.3711388e-08f, 0.3826834323650898f, 0.7071067811865476f,
                             0.9238795325112867f, 1.0f, 0.9238795325112867f,
                             0.7071067811865476f, 0.3826834323650898f };
        const float S[8] = { -1.0f, -0.9238795325112867f, -0.7071067811865476f,
                             -0.3826834323650898f, 0.0f, 0.3826834323650898f,
                             0.7071067811865476f, 0.9238795325112867f };
        const float c = C[a];
        const float s = S[a];

        const float* __restrict__ p =
            pcd + ((size_t)b * NPTS + (size_t)chunk * ROT_CHPTS) * 3;

        for (int n = tid; n < ROT_CHPTS; n += 256) {
            const float x = p[n * 3 + 0];
            const float y = p[n * 3 + 1];
            const float z = p[n * 3 + 2];
            const float rx = x * c - y * s + 5.5f;
            const float ry = x * s + y * c + 5.5f;
            const float rz = z + 2.5f;
            const int icx = (int)floorf(rx);
            const int icy = (int)floorf(ry);
            const int icz = (int)floorf(rz);
            const int flat = icz + icy * 5 + icx * 55;
            if (flat >= 0 && flat < LVOX) atomicAdd(&h[flat], 1);
        }
        __syncthreads();

        int* __restrict__ dst = rot_hist + (size_t)ab * LVOX;
        for (int i = tid; i < LVOX; i += 256) {
            const int v = h[i];
            if (v) atomicAdd(&dst[i], v);
        }
    }
}

// ---------------------------------------------------------------------------
// Finalize.  16-lane groups; bin q lives in ull word w = ((q&1)<<1)|((q>>1)&1),
// 16-bit slot q>>2.  Prefix-scan, write features + rot channels.
// ---------------------------------------------------------------------------
__global__ __launch_bounds__(256) void write_kernel(const int* __restrict__ rot_hist,
                                                    const unsigned* __restrict__ feat_hist32,
                                                    float* __restrict__ out) {
    const int gt    = blockIdx.x * 256 + threadIdx.x;
    const int group = gt >> 4;                 // (b,l)
    const int q     = gt & 15;
    if (group >= BATCH * LVOX) return;
    const int b = group / LVOX;
    const int l = group % LVOX;

    const int w    = ((q & 1) << 1) | ((q >> 1) & 1);
    const int slot = q >> 2;
    const unsigned word = feat_hist32[(size_t)group * 8 + w * 2 + (slot >> 1)];
    int v = (int)((word >> (16 * (slot & 1))) & 0xFFFFu);
#pragma unroll
    for (int off = 1; off < 16; off <<= 1) {
        const int t = __shfl_up(v, off, 16);
        if (q >= off) v += t;
    }
    const float inv_n = 1.0f / (float)NPTS;
    float* __restrict__ o = out + (size_t)group * CH;
    if (q < 15) o[q] = (float)v * inv_n;
    if (q < 8) {
        const int r = rot_hist[((size_t)q * BATCH + b) * LVOX + l];
        o[15 + q] = (float)r * inv_n;
    }
}

extern "C" void kernel_launch(void* const* d_in, const int* in_sizes, int n_in,
                              void* d_out, int out_size, void* d_ws, size_t ws_size,
                              hipStream_t stream) {
    const float* pcd = (const float*)d_in[0];
    float* out = (float*)d_out;
    int* rot_hist = (int*)d_ws;
    unsigned long long* feat_hist =
        (unsigned long long*)((char*)d_ws + (size_t)ROT_WS_INTS * sizeof(int));

    hipLaunchKernelGGL(zero_kernel, dim3((WS_ULL_TOTAL + 255) / 256), dim3(256), 0,
                       stream, (unsigned long long*)d_ws);
    hipLaunchKernelGGL(main_kernel, dim3(FEAT_BLOCKS + ROT_BLOCKS), dim3(256), 0,
                       stream, pcd, rot_hist, feat_hist);
    hipLaunchKernelGGL(write_kernel, dim3((BATCH * LVOX * 16 + 255) / 256), dim3(256),
                       0, stream, rot_hist, (const unsigned*)feat_hist, out);
}

// Round 8
// 56.752 us; speedup vs baseline: 1.0217x; 1.0217x over previous
//
#include <hip/hip_runtime.h>

#define BATCH  8
#define NPTS   16384
#define LVOX   605     // 11*11*5 = 121 xy-columns * 5 z
#define ABINS  8
#define CH     23
#define NCOL   121
#define SPTS   32      // points per 128-lane group
#define GRPS   4       // groups per block (512 threads)
#define BPTS   (SPTS * GRPS)          // 128 points per feature block
#define FEAT_BLOCKS (BATCH * (NPTS / BPTS))   // 8*128 = 1024
#define ROT_CH    4
#define ROT_CHPTS (NPTS / ROT_CH)             // 4096
#define ROT_BLOCKS (ABINS * BATCH * ROT_CH)   // 256

#define ROT_WS_INTS (ABINS * BATCH * LVOX)    // 38720 ints  = 154880 B
#define FEAT_WS_ULL (BATCH * LVOX * 4)        // 19360 ull   = 154880 B
#define WS_ULL_TOTAL (ROT_WS_INTS / 2 + FEAT_WS_ULL)   // 38720 ull

#define MASK8  0x0F0F0F0F0F0F0F0Full
#define MASK16 0x00FF00FF00FF00FFull

// ---------------------------------------------------------------------------
// Workspace zeroing (310 KB) — own kernel, no hipMemsetAsync.
// ---------------------------------------------------------------------------
__global__ __launch_bounds__(256) void zero_kernel(unsigned long long* __restrict__ ws) {
    const int i = blockIdx.x * 256 + threadIdx.x;
    if (i < WS_ULL_TOTAL) ws[i] = 0ull;
}

// ---------------------------------------------------------------------------
// Fused kernel, 512 threads.  Blocks [0,1024): distance features.
// Lane = xy-column, 5 z-locs/lane share rxy2; 32 points per 128-lane group
// via wave-uniform scalar loads.  Nibble-packed bins -> byte counters ->
// ds_add_u64 into ONE shared [5][2][129] histogram (10.3 KB LDS; occupancy
// is wave-slot-bound, 32 waves/CU) -> packed-16-bit global atomics.
// Blocks [1024,1280): rotation-voxel histogram (a,b) x 4 point chunks.
// ---------------------------------------------------------------------------
__global__ __launch_bounds__(512) void main_kernel(const float* __restrict__ pcd,
                                                   int* __restrict__ rot_hist,
                                                   unsigned long long* __restrict__ feat_hist) {
    __shared__ unsigned long long hist[5][2][129];   // 10.3 KB
    const int bid = blockIdx.x;
    const int tid = threadIdx.x;

    if (bid < FEAT_BLOCKS) {
        const int b     = bid >> 7;       // /128
        const int outer = bid & 127;
        // group id is wave-uniform (128 = 2 waves); prove it for s_load.
        const int g4 = __builtin_amdgcn_readfirstlane(tid >> 7);
        const int li = tid & 127;
        const int cc = (li < NCOL) ? li : (NCOL - 1);
        const float lx = -5.0f + (float)(cc / 11);
        const float ly = -5.0f + (float)(cc % 11);

        // zero the shared histogram
        unsigned long long* hp = &hist[0][0][0];
        for (int i = tid; i < 5 * 2 * 129; i += 512) hp[i] = 0ull;

        const float* __restrict__ pp =
            pcd + ((size_t)b * NPTS + outer * BPTS + g4 * SPTS) * 3;

        unsigned long long be0 = 0, bo0 = 0, be1 = 0, bo1 = 0, be2 = 0, bo2 = 0,
                           be3 = 0, bo3 = 0, be4 = 0, bo4 = 0;

        __syncthreads();

        // bin = floor(d) (== ceil(d)-1 a.e.); geometry => bin <= 13, no clamp.
#define PT(J)                                                                   \
        {                                                                       \
            const float x  = pp[(J) * 3 + 0];                                   \
            const float y  = pp[(J) * 3 + 1];                                   \
            const float zp = pp[(J) * 3 + 2];                                   \
            const float dx = x - lx, dy = y - ly;                               \
            const float rxy2 = fmaf(dy, dy, dx * dx);                           \
            const float dz0 = zp + 2.0f;                                        \
            { const float dz = dz0;        const float d = __builtin_amdgcn_sqrtf(fmaf(dz, dz, rxy2)); n0 += 1ull << (((int)d) << 2); } \
            { const float dz = dz0 - 1.0f; const float d = __builtin_amdgcn_sqrtf(fmaf(dz, dz, rxy2)); n1 += 1ull << (((int)d) << 2); } \
            { const float dz = dz0 - 2.0f; const float d = __builtin_amdgcn_sqrtf(fmaf(dz, dz, rxy2)); n2 += 1ull << (((int)d) << 2); } \
            { const float dz = dz0 - 3.0f; const float d = __builtin_amdgcn_sqrtf(fmaf(dz, dz, rxy2)); n3 += 1ull << (((int)d) << 2); } \
            { const float dz = dz0 - 4.0f; const float d = __builtin_amdgcn_sqrtf(fmaf(dz, dz, rxy2)); n4 += 1ull << (((int)d) << 2); } \
        }

#define MERGE()                                                                 \
        be0 += n0 & MASK8; bo0 += (n0 >> 4) & MASK8;                            \
        be1 += n1 & MASK8; bo1 += (n1 >> 4) & MASK8;                            \
        be2 += n2 & MASK8; bo2 += (n2 >> 4) & MASK8;                            \
        be3 += n3 & MASK8; bo3 += (n3 >> 4) & MASK8;                            \
        be4 += n4 & MASK8; bo4 += (n4 >> 4) & MASK8;

#pragma unroll 1
        for (int grp = 0; grp < 2; ++grp) {       // 2 groups of 15 points
            const int base = grp * 15;
            unsigned long long n0 = 0, n1 = 0, n2 = 0, n3 = 0, n4 = 0;
#pragma unroll
            for (int j = 0; j < 15; ++j) PT(base + j)
            MERGE()
        }
        {                                          // tail: points 30..31
            unsigned long long n0 = 0, n1 = 0, n2 = 0, n3 = 0, n4 = 0;
#pragma unroll
            for (int j = 30; j < 32; ++j) PT(j)
            MERGE()
        }
#undef PT
#undef MERGE

        // merge groups via LDS atomics (byte counters: max 4*32=128 < 256)
        atomicAdd(&hist[0][0][li], be0);  atomicAdd(&hist[0][1][li], bo0);
        atomicAdd(&hist[1][0][li], be1);  atomicAdd(&hist[1][1][li], bo1);
        atomicAdd(&hist[2][0][li], be2);  atomicAdd(&hist[2][1][li], bo2);
        atomicAdd(&hist[3][0][li], be3);  atomicAdd(&hist[3][1][li], bo3);
        atomicAdd(&hist[4][0][li], be4);  atomicAdd(&hist[4][1][li], bo4);
        __syncthreads();

        // combine (byte domain -> 16-bit domain), 2 global atomics per item
        for (int item = tid; item < LVOX * 2; item += 512) {
            const int loc = item >> 1;
            const int eo  = item & 1;
            const int col = loc / 5;
            const int z   = loc % 5;
            const unsigned long long v = hist[z][eo][col];
            const unsigned long long slo = v & MASK16;
            const unsigned long long shi = (v >> 8) & MASK16;
            unsigned long long* __restrict__ dst =
                feat_hist + ((size_t)b * LVOX + loc) * 4 + eo * 2;
            atomicAdd(&dst[0], slo);
            atomicAdd(&dst[1], shi);
        }
    } else {
        // ------------------ rotation-voxel histogram ------------------
        const int rb    = bid - FEAT_BLOCKS;
        const int ab    = rb & 63;        // a*8 + b
        const int chunk = rb >> 6;        // 0..3
        const int a     = ab >> 3;
        const int b     = ab & 7;

        int* h = (int*)&hist[0][0][0];
        for (int i = tid; i < LVOX; i += 512) h[i] = 0;
        __syncthreads();

        const float C[8] = { -4.3711388e-08f, 0.3826834323650898f, 0.7071067811865476f,
                             0.9238795325112867f, 1.0f, 0.9238795325112867f,
                             0.7071067811865476f, 0.3826834323650898f };
        const float S[8] = { -1.0f, -0.9238795325112867f, -0.7071067811865476f,
                             -0.3826834323650898f, 0.0f, 0.3826834323650898f,
                             0.7071067811865476f, 0.9238795325112867f };
        const float c = C[a];
        const float s = S[a];

        const float* __restrict__ p =
            pcd + ((size_t)b * NPTS + (size_t)chunk * ROT_CHPTS) * 3;

        for (int n = tid; n < ROT_CHPTS; n += 512) {
            const float x = p[n * 3 + 0];
            const float y = p[n * 3 + 1];
            const float z = p[n * 3 + 2];
            const float rx = x * c - y * s + 5.5f;
            const float ry = x * s + y * c + 5.5f;
            const float rz = z + 2.5f;
            const int icx = (int)floorf(rx);
            const int icy = (int)floorf(ry);
            const int icz = (int)floorf(rz);
            const int flat = icz + icy * 5 + icx * 55;
            if (flat >= 0 && flat < LVOX) atomicAdd(&h[flat], 1);
        }
        __syncthreads();

        int* __restrict__ dst = rot_hist + (size_t)ab * LVOX;
        for (int i = tid; i < LVOX; i += 512) {
            const int v = h[i];
            if (v) atomicAdd(&dst[i], v);
        }
    }
}

// ---------------------------------------------------------------------------
// Finalize.  16-lane groups; bin q lives in ull word w = ((q&1)<<1)|((q>>1)&1),
// 16-bit slot q>>2.  Prefix-scan, write features + rot channels.
// ---------------------------------------------------------------------------
__global__ __launch_bounds__(256) void write_kernel(const int* __restrict__ rot_hist,
                                                    const unsigned* __restrict__ feat_hist32,
                                                    float* __restrict__ out) {
    const int gt    = blockIdx.x * 256 + threadIdx.x;
    const int group = gt >> 4;                 // (b,l)
    const int q     = gt & 15;
    if (group >= BATCH * LVOX) return;
    const int b = group / LVOX;
    const int l = group % LVOX;

    const int w    = ((q & 1) << 1) | ((q >> 1) & 1);
    const int slot = q >> 2;
    const unsigned word = feat_hist32[(size_t)group * 8 + w * 2 + (slot >> 1)];
    int v = (int)((word >> (16 * (slot & 1))) & 0xFFFFu);
#pragma unroll
    for (int off = 1; off < 16; off <<= 1) {
        const int t = __shfl_up(v, off, 16);
        if (q >= off) v += t;
    }
    const float inv_n = 1.0f / (float)NPTS;
    float* __restrict__ o = out + (size_t)group * CH;
    if (q < 15) o[q] = (float)v * inv_n;
    if (q < 8) {
        const int r = rot_hist[((size_t)q * BATCH + b) * LVOX + l];
        o[15 + q] = (float)r * inv_n;
    }
}

extern "C" void kernel_launch(void* const* d_in, const int* in_sizes, int n_in,
                              void* d_out, int out_size, void* d_ws, size_t ws_size,
                              hipStream_t stream) {
    const float* pcd = (const float*)d_in[0];
    float* out = (float*)d_out;
    int* rot_hist = (int*)d_ws;
    unsigned long long* feat_hist =
        (unsigned long long*)((char*)d_ws + (size_t)ROT_WS_INTS * sizeof(int));

    hipLaunchKernelGGL(zero_kernel, dim3((WS_ULL_TOTAL + 255) / 256), dim3(256), 0,
                       stream, (unsigned long long*)d_ws);
    hipLaunchKernelGGL(main_kernel, dim3(FEAT_BLOCKS + ROT_BLOCKS), dim3(512), 0,
                       stream, pcd, rot_hist, feat_hist);
    hipLaunchKernelGGL(write_kernel, dim3((BATCH * LVOX * 16 + 255) / 256), dim3(256),
                       0, stream, rot_hist, (const unsigned*)feat_hist, out);
}

// Round 9
// 44.378 us; speedup vs baseline: 1.3065x; 1.2788x over previous
//
#include <hip/hip_runtime.h>

#define BATCH  8
#define NPTS   16384
#define LVOX   605     // 11*11*5 = 121 xy-columns * 5 z
#define ABINS  8
#define CH     23
#define NCOL   121
#define SPTS   64      // points per 128-lane group
#define GRPS   4       // groups per block (512 threads)
#define BPTS   (SPTS * GRPS)          // 256 points per feature block
#define FEAT_BLOCKS (BATCH * (NPTS / BPTS))   // 8*64 = 512
#define ROT_CH    4
#define ROT_CHPTS (NPTS / ROT_CH)             // 4096
#define ROT_BLOCKS (ABINS * BATCH * ROT_CH)   // 256

#define ROT_WS_INTS (ABINS * BATCH * LVOX)    // 38720 ints  = 154880 B
#define FEAT_WS_ULL (BATCH * LVOX * 4)        // 19360 ull   = 154880 B
#define WS_ULL_TOTAL (ROT_WS_INTS / 2 + FEAT_WS_ULL)   // 38720 ull

#define MASK8  0x0F0F0F0F0F0F0F0Full
#define MASK16 0x00FF00FF00FF00FFull

// ---------------------------------------------------------------------------
// Workspace zeroing (310 KB) — own kernel, no hipMemsetAsync.
// ---------------------------------------------------------------------------
__global__ __launch_bounds__(256) void zero_kernel(unsigned long long* __restrict__ ws) {
    const int i = blockIdx.x * 256 + threadIdx.x;
    if (i < WS_ULL_TOTAL) ws[i] = 0ull;
}

// ---------------------------------------------------------------------------
// Fused kernel, 512 threads = R5 structure (best known: main ~38.5us) with
// two codegen changes: __launch_bounds__(512,4) raises the VGPR cap to ~128
// (R5-R8 allocated only 40 VGPRs -> no ILP, VALUBusy stuck at 40%), and the
// group loop is FULLY unrolled so the scheduler can hoist scalar loads and
// interleave the independent sqrt chains across group boundaries.
// Blocks [0,512): distance features.  Lane = xy-column, 5 z-locs/lane share
// rxy2; 64 points per 128-lane group via wave-uniform scalar loads.
// Blocks [512,768): rotation-voxel histogram.
// ---------------------------------------------------------------------------
__global__ __launch_bounds__(512, 4) void main_kernel(const float* __restrict__ pcd,
                                                      int* __restrict__ rot_hist,
                                                      unsigned long long* __restrict__ feat_hist) {
    __shared__ unsigned long long lds[5][2][GRPS][129];   // 41.3 KB
    const int bid = blockIdx.x;
    const int tid = threadIdx.x;

    if (bid < FEAT_BLOCKS) {
        const int b     = bid >> 6;      // /64
        const int outer = bid & 63;
        // group id is wave-uniform (128 = 2 waves); prove it for s_load.
        const int g4 = __builtin_amdgcn_readfirstlane(tid >> 7);
        const int li = tid & 127;
        const int cc = (li < NCOL) ? li : (NCOL - 1);
        const float lx = -5.0f + (float)(cc / 11);
        const float ly = -5.0f + (float)(cc % 11);

        const float* __restrict__ pp =
            pcd + ((size_t)b * NPTS + outer * BPTS + g4 * SPTS) * 3;

        unsigned long long be0 = 0, bo0 = 0, be1 = 0, bo1 = 0, be2 = 0, bo2 = 0,
                           be3 = 0, bo3 = 0, be4 = 0, bo4 = 0;

        // bin = floor(d) (== ceil(d)-1 a.e.); geometry => bin <= 13, no clamp.
#define PT(J)                                                                   \
        {                                                                       \
            const float x  = pp[(J) * 3 + 0];                                   \
            const float y  = pp[(J) * 3 + 1];                                   \
            const float zp = pp[(J) * 3 + 2];                                   \
            const float dx = x - lx, dy = y - ly;                               \
            const float rxy2 = fmaf(dy, dy, dx * dx);                           \
            const float dz0 = zp + 2.0f;                                        \
            { const float dz = dz0;        const float d = __builtin_amdgcn_sqrtf(fmaf(dz, dz, rxy2)); n0 += 1ull << (((int)d) << 2); } \
            { const float dz = dz0 - 1.0f; const float d = __builtin_amdgcn_sqrtf(fmaf(dz, dz, rxy2)); n1 += 1ull << (((int)d) << 2); } \
            { const float dz = dz0 - 2.0f; const float d = __builtin_amdgcn_sqrtf(fmaf(dz, dz, rxy2)); n2 += 1ull << (((int)d) << 2); } \
            { const float dz = dz0 - 3.0f; const float d = __builtin_amdgcn_sqrtf(fmaf(dz, dz, rxy2)); n3 += 1ull << (((int)d) << 2); } \
            { const float dz = dz0 - 4.0f; const float d = __builtin_amdgcn_sqrtf(fmaf(dz, dz, rxy2)); n4 += 1ull << (((int)d) << 2); } \
        }

#define MERGE()                                                                 \
        be0 += n0 & MASK8; bo0 += (n0 >> 4) & MASK8;                            \
        be1 += n1 & MASK8; bo1 += (n1 >> 4) & MASK8;                            \
        be2 += n2 & MASK8; bo2 += (n2 >> 4) & MASK8;                            \
        be3 += n3 & MASK8; bo3 += (n3 >> 4) & MASK8;                            \
        be4 += n4 & MASK8; bo4 += (n4 >> 4) & MASK8;

#pragma unroll
        for (int grp = 0; grp < 4; ++grp) {       // FULLY unrolled: 4 x 15 pts
            const int base = grp * 15;
            unsigned long long n0 = 0, n1 = 0, n2 = 0, n3 = 0, n4 = 0;
#pragma unroll
            for (int j = 0; j < 15; ++j) PT(base + j)
            MERGE()
        }
        {                                          // tail: points 60..63
            unsigned long long n0 = 0, n1 = 0, n2 = 0, n3 = 0, n4 = 0;
#pragma unroll
            for (int j = 60; j < 64; ++j) PT(j)
            MERGE()
        }
#undef PT
#undef MERGE

        lds[0][0][g4][li] = be0;  lds[0][1][g4][li] = bo0;
        lds[1][0][g4][li] = be1;  lds[1][1][g4][li] = bo1;
        lds[2][0][g4][li] = be2;  lds[2][1][g4][li] = bo2;
        lds[3][0][g4][li] = be3;  lds[3][1][g4][li] = bo3;
        lds[4][0][g4][li] = be4;  lds[4][1][g4][li] = bo4;
        __syncthreads();

        // combine 4 groups (byte domain -> 16-bit domain), 2 atomics per item
        for (int item = tid; item < LVOX * 2; item += 512) {
            const int loc = item >> 1;
            const int eo  = item & 1;
            const int col = loc / 5;
            const int z   = loc % 5;
            unsigned long long slo = 0, shi = 0;
#pragma unroll
            for (int g = 0; g < GRPS; ++g) {
                const unsigned long long v = lds[z][eo][g][col];
                slo += v & MASK16;
                shi += (v >> 8) & MASK16;
            }
            unsigned long long* __restrict__ dst =
                feat_hist + ((size_t)b * LVOX + loc) * 4 + eo * 2;
            atomicAdd(&dst[0], slo);
            atomicAdd(&dst[1], shi);
        }
    } else {
        // ------------------ rotation-voxel histogram ------------------
        const int rb    = bid - FEAT_BLOCKS;
        const int ab    = rb & 63;        // a*8 + b
        const int chunk = rb >> 6;        // 0..3
        const int a     = ab >> 3;
        const int b     = ab & 7;

        int* h = (int*)&lds[0][0][0][0];
        for (int i = tid; i < LVOX; i += 512) h[i] = 0;
        __syncthreads();

        const float C[8] = { -4.3711388e-08f, 0.3826834323650898f, 0.7071067811865476f,
                             0.9238795325112867f, 1.0f, 0.9238795325112867f,
                             0.7071067811865476f, 0.3826834323650898f };
        const float S[8] = { -1.0f, -0.9238795325112867f, -0.7071067811865476f,
                             -0.3826834323650898f, 0.0f, 0.3826834323650898f,
                             0.7071067811865476f, 0.9238795325112867f };
        const float c = C[a];
        const float s = S[a];

        const float* __restrict__ p =
            pcd + ((size_t)b * NPTS + (size_t)chunk * ROT_CHPTS) * 3;

        for (int n = tid; n < ROT_CHPTS; n += 512) {
            const float x = p[n * 3 + 0];
            const float y = p[n * 3 + 1];
            const float z = p[n * 3 + 2];
            const float rx = x * c - y * s + 5.5f;
            const float ry = x * s + y * c + 5.5f;
            const float rz = z + 2.5f;
            const int icx = (int)floorf(rx);
            const int icy = (int)floorf(ry);
            const int icz = (int)floorf(rz);
            const int flat = icz + icy * 5 + icx * 55;
            if (flat >= 0 && flat < LVOX) atomicAdd(&h[flat], 1);
        }
        __syncthreads();

        int* __restrict__ dst = rot_hist + (size_t)ab * LVOX;
        for (int i = tid; i < LVOX; i += 512) {
            const int v = h[i];
            if (v) atomicAdd(&dst[i], v);
        }
    }
}

// ---------------------------------------------------------------------------
// Finalize.  16-lane groups; bin q lives in ull word w = ((q&1)<<1)|((q>>1)&1),
// 16-bit slot q>>2.  Prefix-scan, write features + rot channels.
// ---------------------------------------------------------------------------
__global__ __launch_bounds__(256) void write_kernel(const int* __restrict__ rot_hist,
                                                    const unsigned* __restrict__ feat_hist32,
                                                    float* __restrict__ out) {
    const int gt    = blockIdx.x * 256 + threadIdx.x;
    const int group = gt >> 4;                 // (b,l)
    const int q     = gt & 15;
    if (group >= BATCH * LVOX) return;
    const int b = group / LVOX;
    const int l = group % LVOX;

    const int w    = ((q & 1) << 1) | ((q >> 1) & 1);
    const int slot = q >> 2;
    const unsigned word = feat_hist32[(size_t)group * 8 + w * 2 + (slot >> 1)];
    int v = (int)((word >> (16 * (slot & 1))) & 0xFFFFu);
#pragma unroll
    for (int off = 1; off < 16; off <<= 1) {
        const int t = __shfl_up(v, off, 16);
        if (q >= off) v += t;
    }
    const float inv_n = 1.0f / (float)NPTS;
    float* __restrict__ o = out + (size_t)group * CH;
    if (q < 15) o[q] = (float)v * inv_n;
    if (q < 8) {
        const int r = rot_hist[((size_t)q * BATCH + b) * LVOX + l];
        o[15 + q] = (float)r * inv_n;
    }
}

extern "C" void kernel_launch(void* const* d_in, const int* in_sizes, int n_in,
                              void* d_out, int out_size, void* d_ws, size_t ws_size,
                              hipStream_t stream) {
    const float* pcd = (const float*)d_in[0];
    float* out = (float*)d_out;
    int* rot_hist = (int*)d_ws;
    unsigned long long* feat_hist =
        (unsigned long long*)((char*)d_ws + (size_t)ROT_WS_INTS * sizeof(int));

    hipLaunchKernelGGL(zero_kernel, dim3((WS_ULL_TOTAL + 255) / 256), dim3(256), 0,
                       stream, (unsigned long long*)d_ws);
    hipLaunchKernelGGL(main_kernel, dim3(FEAT_BLOCKS + ROT_BLOCKS), dim3(512), 0,
                       stream, pcd, rot_hist, feat_hist);
    hipLaunchKernelGGL(write_kernel, dim3((BATCH * LVOX * 16 + 255) / 256), dim3(256),
                       0, stream, rot_hist, (const unsigned*)feat_hist, out);
}